// Round 2
// baseline (200.062 us; speedup 1.0000x reference)
//
#include <hip/hip_runtime.h>
#include <math.h>

// SelfNorm: out = (x - mean)*std_w + mean*mean_w  (per (b,c) plane over H*W)
// where mean/std are plane stats (ddof=1, +EPS inside sqrt) and
// mean_w/std_w = sigmoid(W2·relu(W1·[mean,std]+b1)+b2) tiny MLPs.
// Algebra: x_norm*(s*std_w) + m*mean_w == x*std_w + m*(mean_w - std_w).
// Pure HBM-bound: 1 read + 1 write of x (2 x 102.8 MB).

constexpr int N_HW  = 56 * 56;   // 3136 elements per (b,c) plane
constexpr int N_V4  = N_HW / 4;  // 784 float4s (12544 bytes, 16B-aligned)
constexpr int BLOCK = 256;       // 4 waves
constexpr float EPS = 1e-5f;

__global__ __launch_bounds__(BLOCK) void selfnorm_kernel(
    const float* __restrict__ x,
    const float* __restrict__ W1m, const float* __restrict__ b1m,
    const float* __restrict__ W2m, const float* __restrict__ b2m,
    const float* __restrict__ W1s, const float* __restrict__ b1s,
    const float* __restrict__ W2s, const float* __restrict__ b2s,
    float* __restrict__ out)
{
    __shared__ float plane[N_HW];   // 12.5 KB: stage plane so HBM read happens once
    __shared__ float red[8];        // per-wave {sum, sumsq}, 4 waves
    __shared__ float bcast[4];      // mean, mean_w, std_w

    const long long base = (long long)blockIdx.x * N_HW;  // blockIdx.x = b*256 + c
    const float4* __restrict__ src = (const float4*)(x + base);
    float4* __restrict__ dst       = (float4*)(out + base);
    float4* planev                 = (float4*)plane;

    const int tid = threadIdx.x;

    // ---- pass 1: global -> LDS, accumulate sum / sumsq ----
    float sum = 0.f, sumsq = 0.f;
    for (int i = tid; i < N_V4; i += BLOCK) {
        float4 v = src[i];
        planev[i] = v;
        sum   += (v.x + v.y) + (v.z + v.w);
        sumsq += (v.x * v.x + v.y * v.y) + (v.z * v.z + v.w * v.w);
    }

    // ---- wave (64-lane) reduction, then cross-wave via LDS ----
    #pragma unroll
    for (int off = 32; off > 0; off >>= 1) {
        sum   += __shfl_down(sum, off, 64);
        sumsq += __shfl_down(sumsq, off, 64);
    }
    const int wave = tid >> 6;
    if ((tid & 63) == 0) {
        red[wave * 2 + 0] = sum;
        red[wave * 2 + 1] = sumsq;
    }
    __syncthreads();

    if (tid == 0) {
        float s  = (red[0] + red[2]) + (red[4] + red[6]);
        float sq = (red[1] + red[3]) + (red[5] + red[7]);
        float mean = s * (1.0f / (float)N_HW);
        float var  = (sq - s * mean) * (1.0f / (float)(N_HW - 1));  // ddof=1
        float stdv = sqrtf(var + EPS);

        // two tiny MLPs: 2 -> 16 (relu) -> 1 (sigmoid); weights are L2-resident
        float accm = b2m[0];
        float accs = b2s[0];
        #pragma unroll
        for (int j = 0; j < 16; ++j) {
            float hm = fmaf(W1m[j * 2 + 1], stdv, fmaf(W1m[j * 2], mean, b1m[j]));
            accm = fmaf(W2m[j], fmaxf(hm, 0.f), accm);
            float hs = fmaf(W1s[j * 2 + 1], stdv, fmaf(W1s[j * 2], mean, b1s[j]));
            accs = fmaf(W2s[j], fmaxf(hs, 0.f), accs);
        }
        float mean_w = 1.0f / (1.0f + expf(-accm));
        float std_w  = 1.0f / (1.0f + expf(-accs));

        bcast[0] = mean;
        bcast[1] = mean_w;
        bcast[2] = std_w;
    }
    __syncthreads();

    // out = x*std_w + m*(mean_w - std_w)
    const float mean = bcast[0];
    const float a    = bcast[2];                      // std_w
    const float bb   = mean * (bcast[1] - bcast[2]);  // m*(mean_w - std_w)

    for (int i = tid; i < N_V4; i += BLOCK) {
        float4 v = planev[i];
        float4 o;
        o.x = fmaf(v.x, a, bb);
        o.y = fmaf(v.y, a, bb);
        o.z = fmaf(v.z, a, bb);
        o.w = fmaf(v.w, a, bb);
        dst[i] = o;
    }
}

extern "C" void kernel_launch(void* const* d_in, const int* in_sizes, int n_in,
                              void* d_out, int out_size, void* d_ws, size_t ws_size,
                              hipStream_t stream) {
    const float* x   = (const float*)d_in[0];
    const float* W1m = (const float*)d_in[1];
    const float* b1m = (const float*)d_in[2];
    const float* W2m = (const float*)d_in[3];
    const float* b2m = (const float*)d_in[4];
    const float* W1s = (const float*)d_in[5];
    const float* b1s = (const float*)d_in[6];
    const float* W2s = (const float*)d_in[7];
    const float* b2s = (const float*)d_in[8];
    float* out = (float*)d_out;

    const int planes = 32 * 256;  // B*C = 8192 blocks, one per (b,c) plane
    selfnorm_kernel<<<planes, BLOCK, 0, stream>>>(
        x, W1m, b1m, W2m, b2m, W1s, b1s, W2s, b2s, out);
}

// Round 4
// 194.660 us; speedup vs baseline: 1.0277x; 1.0277x over previous
//
#include <hip/hip_runtime.h>
#include <math.h>

// SelfNorm: out = (x - mean)*std_w + mean*mean_w  (per (b,c) plane over H*W)
// Algebra: x_norm*(s*std_w) + m*mean_w == x*std_w + m*(mean_w - std_w).
// Register-resident plane: 784 float4 = 256 thr x 3 (+16 tail), single barrier,
// redundant per-thread MLP (weights scalarized to s_load), NT stores.

typedef float f32x4 __attribute__((ext_vector_type(4)));  // clang-native vec4

constexpr int N_HW  = 56 * 56;   // 3136 elements per (b,c) plane
constexpr int BLOCK = 256;       // 4 waves
constexpr float EPS = 1e-5f;

__global__ __launch_bounds__(BLOCK) void selfnorm_kernel(
    const float* __restrict__ x,
    const float* __restrict__ W1m, const float* __restrict__ b1m,
    const float* __restrict__ W2m, const float* __restrict__ b2m,
    const float* __restrict__ W1s, const float* __restrict__ b1s,
    const float* __restrict__ W2s, const float* __restrict__ b2s,
    float* __restrict__ out)
{
    __shared__ float red[8];  // per-wave {sum, sumsq}

    const long long base = (long long)blockIdx.x * N_HW;  // blockIdx.x = b*256 + c
    const f32x4* __restrict__ src = (const f32x4*)(x + base);
    f32x4* __restrict__ dst       = (f32x4*)(out + base);
    const int tid = threadIdx.x;

    // ---- all loads issue back-to-back: max memory-level parallelism ----
    f32x4 r0 = src[tid];
    f32x4 r1 = src[tid + 256];
    f32x4 r2 = src[tid + 512];
    f32x4 r3 = (f32x4){0.f, 0.f, 0.f, 0.f};
    if (tid < 16) r3 = src[tid + 768];

    float sum   = (r0.x + r0.y + r0.z + r0.w)
                + (r1.x + r1.y + r1.z + r1.w)
                + (r2.x + r2.y + r2.z + r2.w)
                + (r3.x + r3.y + r3.z + r3.w);
    float sumsq = (r0.x*r0.x + r0.y*r0.y + r0.z*r0.z + r0.w*r0.w)
                + (r1.x*r1.x + r1.y*r1.y + r1.z*r1.z + r1.w*r1.w)
                + (r2.x*r2.x + r2.y*r2.y + r2.z*r2.z + r2.w*r2.w)
                + (r3.x*r3.x + r3.y*r3.y + r3.z*r3.z + r3.w*r3.w);

    // ---- wave (64-lane) butterfly, lane0 -> LDS; single barrier ----
    #pragma unroll
    for (int off = 32; off > 0; off >>= 1) {
        sum   += __shfl_down(sum, off, 64);
        sumsq += __shfl_down(sumsq, off, 64);
    }
    const int wave = tid >> 6;
    if ((tid & 63) == 0) {
        red[wave * 2 + 0] = sum;
        red[wave * 2 + 1] = sumsq;
    }
    __syncthreads();

    // ---- every thread redundantly computes stats + both MLPs ----
    // (weight addresses are wave-uniform -> scalar loads, hoisted by compiler)
    const float s  = (red[0] + red[2]) + (red[4] + red[6]);
    const float sq = (red[1] + red[3]) + (red[5] + red[7]);
    const float mean = s * (1.0f / (float)N_HW);
    const float var  = (sq - s * mean) * (1.0f / (float)(N_HW - 1));  // ddof=1
    const float stdv = sqrtf(var + EPS);

    float accm = b2m[0];
    float accs = b2s[0];
    #pragma unroll
    for (int j = 0; j < 16; ++j) {
        float hm = fmaf(W1m[j * 2 + 1], stdv, fmaf(W1m[j * 2], mean, b1m[j]));
        accm = fmaf(W2m[j], fmaxf(hm, 0.f), accm);
        float hs = fmaf(W1s[j * 2 + 1], stdv, fmaf(W1s[j * 2], mean, b1s[j]));
        accs = fmaf(W2s[j], fmaxf(hs, 0.f), accs);
    }
    const float mean_w = 1.0f / (1.0f + expf(-accm));
    const float std_w  = 1.0f / (1.0f + expf(-accs));

    // out = x*std_w + m*(mean_w - std_w)
    const float a  = std_w;
    const float bb = mean * (mean_w - std_w);

    f32x4 o0, o1, o2, o3;
    o0.x = fmaf(r0.x, a, bb); o0.y = fmaf(r0.y, a, bb);
    o0.z = fmaf(r0.z, a, bb); o0.w = fmaf(r0.w, a, bb);
    o1.x = fmaf(r1.x, a, bb); o1.y = fmaf(r1.y, a, bb);
    o1.z = fmaf(r1.z, a, bb); o1.w = fmaf(r1.w, a, bb);
    o2.x = fmaf(r2.x, a, bb); o2.y = fmaf(r2.y, a, bb);
    o2.z = fmaf(r2.z, a, bb); o2.w = fmaf(r2.w, a, bb);
    o3.x = fmaf(r3.x, a, bb); o3.y = fmaf(r3.y, a, bb);
    o3.z = fmaf(r3.z, a, bb); o3.w = fmaf(r3.w, a, bb);

    // NT stores: output is never re-read; don't evict the L3-warm input.
    __builtin_nontemporal_store(o0, &dst[tid]);
    __builtin_nontemporal_store(o1, &dst[tid + 256]);
    __builtin_nontemporal_store(o2, &dst[tid + 512]);
    if (tid < 16) __builtin_nontemporal_store(o3, &dst[tid + 768]);
}

extern "C" void kernel_launch(void* const* d_in, const int* in_sizes, int n_in,
                              void* d_out, int out_size, void* d_ws, size_t ws_size,
                              hipStream_t stream) {
    const float* x   = (const float*)d_in[0];
    const float* W1m = (const float*)d_in[1];
    const float* b1m = (const float*)d_in[2];
    const float* W2m = (const float*)d_in[3];
    const float* b2m = (const float*)d_in[4];
    const float* W1s = (const float*)d_in[5];
    const float* b1s = (const float*)d_in[6];
    const float* W2s = (const float*)d_in[7];
    const float* b2s = (const float*)d_in[8];
    float* out = (float*)d_out;

    const int planes = 32 * 256;  // B*C = 8192 blocks, one per (b,c) plane
    selfnorm_kernel<<<planes, BLOCK, 0, stream>>>(
        x, W1m, b1m, W2m, b2m, W1s, b1s, W2s, b2s, out);
}